// Round 1
// baseline (1357.646 us; speedup 1.0000x reference)
//
#include <hip/hip_runtime.h>
#include <hip/hip_bf16.h>

#define LSEQ 2048
#define NB   4
#define EMB  1024
#define NH   16
#define DH   64
#define BH   (NB*NH)   // 64 head-batches
#define SCALE 0.125f   // d^-0.5

typedef unsigned short ushort8 __attribute__((ext_vector_type(8)));

__device__ __forceinline__ float bf_to_f(unsigned short u) {
    return __uint_as_float(((unsigned int)u) << 16);
}
__device__ __forceinline__ unsigned short f_to_bf(float f) {
    unsigned int u = __float_as_uint(f);
    unsigned int r = (u + 0x7fffu + ((u >> 16) & 1u)) >> 16;
    return (unsigned short)r;
}

// ---- wsum[e] = sum_f wout[f][e] ----
__global__ void wsum_kernel(const float* __restrict__ wout, float* __restrict__ wsum) {
    int e = blockIdx.x * 256 + threadIdx.x;
    float s = 0.f;
    #pragma unroll 8
    for (int f = 0; f < EMB; ++f) s += wout[(size_t)f * EMB + e];
    wsum[e] = s;
}

// ---- wv_eff[h][e] = sum_j wqkv[2E + h*64 + j][e] * wsum[h*64+j] ----
__global__ void wveff_kernel(const float* __restrict__ wqkv, const float* __restrict__ wsum,
                             float* __restrict__ wveff) {
    int idx = blockIdx.x * 256 + threadIdx.x;   // h*EMB + e
    int h = idx >> 10, e = idx & 1023;
    float s = 0.f;
    #pragma unroll 8
    for (int j = 0; j < DH; ++j)
        s += wqkv[(size_t)(2 * EMB + h * DH + j) * EMB + e] * wsum[h * DH + j];
    wveff[idx] = s;
}

// ---- vw[b][m] = sum_e x[m,n,e] * wv_eff[h][e],  b=n*NH+h ----
__global__ __launch_bounds__(256) void vw_kernel(const float* __restrict__ x,
                                                 const float* __restrict__ wveff,
                                                 float* __restrict__ vw) {
    int wave = threadIdx.x >> 6;
    int lane = threadIdx.x & 63;
    int r = blockIdx.x * 4 + wave;   // r = l*NB + n
    int n = r & 3, l = r >> 2;
    float acc[NH] = {};
    for (int e = lane; e < EMB; e += 64) {
        float xe = x[(size_t)r * EMB + e];
        #pragma unroll
        for (int h = 0; h < NH; ++h) acc[h] += xe * wveff[h * EMB + e];
    }
    #pragma unroll
    for (int h = 0; h < NH; ++h) {
        float v = acc[h];
        #pragma unroll
        for (int off = 32; off > 0; off >>= 1) v += __shfl_down(v, off, 64);
        if (lane == 0) vw[(size_t)(n * NH + h) * LSEQ + l] = v;
    }
}

// ---- Q/K projection: C[r][c] = dot(x[r,:], wqkv[c,:]);  c<E -> q*SCALE, else k ----
#define BM 64
#define BN 64
#define BK 16
#define PAD 4
__global__ __launch_bounds__(256) void proj_gemm(const float* __restrict__ x,
                                                 const float* __restrict__ wqkv,
                                                 unsigned short* __restrict__ qws,
                                                 unsigned short* __restrict__ kws) {
    __shared__ float As[BK][BM + PAD];
    __shared__ float Bs[BK][BN + PAD];
    const int tid = threadIdx.x;
    const int r0 = blockIdx.y * BM;
    const int c0 = blockIdx.x * BN;
    const int tx = tid & 15, ty = tid >> 4;
    float acc[4][4] = {};
    const int lm = tid >> 2;            // 0..63
    const int lk = (tid & 3) * 4;       // 0,4,8,12
    for (int k0 = 0; k0 < EMB; k0 += BK) {
        float4 va = *reinterpret_cast<const float4*>(&x[(size_t)(r0 + lm) * EMB + k0 + lk]);
        float4 vb = *reinterpret_cast<const float4*>(&wqkv[(size_t)(c0 + lm) * EMB + k0 + lk]);
        As[lk + 0][lm] = va.x; As[lk + 1][lm] = va.y; As[lk + 2][lm] = va.z; As[lk + 3][lm] = va.w;
        Bs[lk + 0][lm] = vb.x; Bs[lk + 1][lm] = vb.y; Bs[lk + 2][lm] = vb.z; Bs[lk + 3][lm] = vb.w;
        __syncthreads();
        #pragma unroll
        for (int kk = 0; kk < BK; ++kk) {
            float4 a = *reinterpret_cast<const float4*>(&As[kk][ty * 4]);
            float4 b = *reinterpret_cast<const float4*>(&Bs[kk][tx * 4]);
            float av[4] = {a.x, a.y, a.z, a.w};
            float bv[4] = {b.x, b.y, b.z, b.w};
            #pragma unroll
            for (int i = 0; i < 4; ++i)
                #pragma unroll
                for (int j = 0; j < 4; ++j) acc[i][j] += av[i] * bv[j];
        }
        __syncthreads();
    }
    #pragma unroll
    for (int i = 0; i < 4; ++i) {
        int r = r0 + ty * 4 + i;
        int n = r & 3, l = r >> 2;
        #pragma unroll
        for (int j = 0; j < 4; ++j) {
            int c = c0 + tx * 4 + j;
            float v = acc[i][j];
            if (c < EMB) {
                int h = c >> 6, jd = c & 63;
                qws[((size_t)(n * NH + h) * LSEQ + l) * DH + jd] = f_to_bf(v * SCALE);
            } else {
                int c2 = c - EMB;
                int h = c2 >> 6, jd = c2 & 63;
                kws[((size_t)(n * NH + h) * LSEQ + l) * DH + jd] = f_to_bf(v);
            }
        }
    }
}

// ---- causal attention with scalar values: o[b,l] = sum_m p*vw / sum_m p ----
#define TL 256
#define TM 64
__global__ __launch_bounds__(256) void attn_kernel(const unsigned short* __restrict__ qws,
                                                   const unsigned short* __restrict__ kws,
                                                   const float* __restrict__ vw,
                                                   float* __restrict__ partials) {
    __shared__ float Ks[TM][DH];
    __shared__ float vs[TM];
    __shared__ float red[256];
    const int b = blockIdx.y;
    const int l0 = blockIdx.x * TL;
    const int tid = threadIdx.x;
    const int l = l0 + tid;

    float q[DH];
    {
        const ushort8* qp = reinterpret_cast<const ushort8*>(&qws[((size_t)b * LSEQ + l) * DH]);
        #pragma unroll
        for (int i = 0; i < 8; ++i) {
            ushort8 u = qp[i];
            #pragma unroll
            for (int j = 0; j < 8; ++j) q[i * 8 + j] = bf_to_f(u[j]);
        }
    }

    float Z = 0.f, O = 0.f;
    const int ntiles = blockIdx.x * (TL / TM) + (TL / TM);
    for (int t = 0; t < ntiles; ++t) {
        int m0 = t * TM;
        {
            int row = tid >> 2;
            int cq = (tid & 3) * 16;
            const ushort8* kp = reinterpret_cast<const ushort8*>(
                &kws[((size_t)b * LSEQ + m0 + row) * DH + cq]);
            ushort8 u0 = kp[0], u1 = kp[1];
            #pragma unroll
            for (int j = 0; j < 8; ++j) Ks[row][cq + j] = bf_to_f(u0[j]);
            #pragma unroll
            for (int j = 0; j < 8; ++j) Ks[row][cq + 8 + j] = bf_to_f(u1[j]);
            if (tid < TM) vs[tid] = vw[(size_t)b * LSEQ + m0 + tid];
        }
        __syncthreads();
        int mmax = l - m0; if (mmax > TM - 1) mmax = TM - 1;
        for (int mm = 0; mm <= mmax; ++mm) {
            const float4* kr = reinterpret_cast<const float4*>(&Ks[mm][0]);
            float s0 = 0.f, s1 = 0.f, s2 = 0.f, s3 = 0.f;
            #pragma unroll
            for (int j4 = 0; j4 < 16; ++j4) {
                float4 kv = kr[j4];
                s0 += q[j4 * 4 + 0] * kv.x;
                s1 += q[j4 * 4 + 1] * kv.y;
                s2 += q[j4 * 4 + 2] * kv.z;
                s3 += q[j4 * 4 + 3] * kv.w;
            }
            float s = (s0 + s1) + (s2 + s3);
            float p = __expf(s - 16.0f);
            Z += p;
            O += p * vs[mm];
        }
        __syncthreads();
    }
    float o = O / Z;
    red[tid] = o;
    __syncthreads();
    for (int sh = 128; sh > 0; sh >>= 1) {
        if (tid < sh) red[tid] += red[tid + sh];
        __syncthreads();
    }
    if (tid == 0) partials[blockIdx.y * gridDim.x + blockIdx.x] = red[0];
}

// ---- final deterministic reduction of 512 partials ----
__global__ void reduce_kernel(const float* __restrict__ partials, float* __restrict__ out) {
    __shared__ float red[256];
    int t = threadIdx.x;
    red[t] = partials[t] + partials[t + 256];
    __syncthreads();
    for (int sh = 128; sh > 0; sh >>= 1) {
        if (t < sh) red[t] += red[t + sh];
        __syncthreads();
    }
    if (t == 0) out[0] = red[0];
}

extern "C" void kernel_launch(void* const* d_in, const int* in_sizes, int n_in,
                              void* d_out, int out_size, void* d_ws, size_t ws_size,
                              hipStream_t stream) {
    const float* x    = (const float*)d_in[0];
    const float* wqkv = (const float*)d_in[1];
    const float* wout = (const float*)d_in[2];
    float* out = (float*)d_out;

    unsigned short* qws = (unsigned short*)d_ws;
    unsigned short* kws = qws + (size_t)BH * LSEQ * DH;
    float* vw       = (float*)(kws + (size_t)BH * LSEQ * DH);
    float* wsum     = vw + (size_t)BH * LSEQ;
    float* wveff    = wsum + EMB;
    float* partials = wveff + NH * EMB;

    hipLaunchKernelGGL(wsum_kernel,  dim3(EMB / 256), dim3(256), 0, stream, wout, wsum);
    hipLaunchKernelGGL(wveff_kernel, dim3(NH * EMB / 256), dim3(256), 0, stream, wqkv, wsum, wveff);
    hipLaunchKernelGGL(vw_kernel,    dim3(LSEQ * NB / 4), dim3(256), 0, stream, x, wveff, vw);
    hipLaunchKernelGGL(proj_gemm,    dim3(2 * EMB / BN, LSEQ * NB / BM), dim3(256), 0, stream,
                       x, wqkv, qws, kws);
    hipLaunchKernelGGL(attn_kernel,  dim3(LSEQ / TL, BH), dim3(256), 0, stream,
                       qws, kws, vw, partials);
    hipLaunchKernelGGL(reduce_kernel, dim3(1), dim3(256), 0, stream, partials, out);
}

// Round 3
// 271.153 us; speedup vs baseline: 5.0069x; 5.0069x over previous
//
#include <hip/hip_runtime.h>
#include <hip/hip_bf16.h>

#define LSEQ 2048
#define NB   4
#define EMB  1024
#define NH   16
#define DH   64
#define BH   (NB*NH)   // 64 head-batches
#define SCALE 0.125f   // d^-0.5

typedef unsigned short ushort8 __attribute__((ext_vector_type(8)));
typedef __attribute__((ext_vector_type(8))) short bf16x8;   // MFMA A/B frag (8 bf16)
typedef __attribute__((ext_vector_type(4))) float f32x4;    // MFMA C/D frag

__device__ __forceinline__ unsigned short f_to_bf(float f) {
    unsigned int u = __float_as_uint(f);
    return (unsigned short)((u + 0x7fffu + ((u >> 16) & 1u)) >> 16);
}

// ---- fp32 -> bf16 bulk convert (8 elems/thread) ----
__global__ __launch_bounds__(256) void tobf16_kernel(const float* __restrict__ in,
                                                     unsigned short* __restrict__ out, int n8) {
    int i = blockIdx.x * 256 + threadIdx.x;
    if (i >= n8) return;
    const float4* p = reinterpret_cast<const float4*>(in) + (size_t)i * 2;
    float4 a = p[0], b = p[1];
    ushort8 o;
    o[0] = f_to_bf(a.x); o[1] = f_to_bf(a.y); o[2] = f_to_bf(a.z); o[3] = f_to_bf(a.w);
    o[4] = f_to_bf(b.x); o[5] = f_to_bf(b.y); o[6] = f_to_bf(b.z); o[7] = f_to_bf(b.w);
    reinterpret_cast<ushort8*>(out)[i] = o;
}

// ---- wsum[e] = sum_f wout[f][e] ----
__global__ void wsum_kernel(const float* __restrict__ wout, float* __restrict__ wsum) {
    int e = blockIdx.x * 256 + threadIdx.x;
    float s = 0.f;
    #pragma unroll 8
    for (int f = 0; f < EMB; ++f) s += wout[(size_t)f * EMB + e];
    wsum[e] = s;
}

// ---- wv_eff[h][e] = sum_j wqkv[2E + h*64 + j][e] * wsum[h*64+j] ----
__global__ void wveff_kernel(const float* __restrict__ wqkv, const float* __restrict__ wsum,
                             float* __restrict__ wveff) {
    int idx = blockIdx.x * 256 + threadIdx.x;   // h*EMB + e
    int h = idx >> 10, e = idx & 1023;
    float s = 0.f;
    #pragma unroll 8
    for (int j = 0; j < DH; ++j)
        s += wqkv[(size_t)(2 * EMB + h * DH + j) * EMB + e] * wsum[h * DH + j];
    wveff[idx] = s;
}

// ---- vw[b][m] = sum_e x[m,n,e] * wv_eff[h][e],  b=n*NH+h ----
__global__ __launch_bounds__(256) void vw_kernel(const float* __restrict__ x,
                                                 const float* __restrict__ wveff,
                                                 float* __restrict__ vw) {
    int wave = threadIdx.x >> 6;
    int lane = threadIdx.x & 63;
    int r = blockIdx.x * 4 + wave;   // r = l*NB + n
    int n = r & 3, l = r >> 2;
    float acc[NH] = {};
    for (int e = lane; e < EMB; e += 64) {
        float xe = x[(size_t)r * EMB + e];
        #pragma unroll
        for (int h = 0; h < NH; ++h) acc[h] += xe * wveff[h * EMB + e];
    }
    #pragma unroll
    for (int h = 0; h < NH; ++h) {
        float v = acc[h];
        #pragma unroll
        for (int off = 32; off > 0; off >>= 1) v += __shfl_down(v, off, 64);
        if (lane == 0) vw[(size_t)(n * NH + h) * LSEQ + l] = v;
    }
}

// ---- bf16 MFMA Q/K projection: C[r][c] = dot(xb[r,:], wb[c,:]) ----
// 128x128 tile, BK=32, 4 waves (2x2), 4x4 16x16x32 fragments per wave.
#define PBM 128
#define PBN 128
#define PBK 32
__global__ __launch_bounds__(256) void proj_mfma(const unsigned short* __restrict__ xb,
                                                 const unsigned short* __restrict__ wb,
                                                 unsigned short* __restrict__ qws,
                                                 unsigned short* __restrict__ kws) {
    __shared__ unsigned short As[PBM * PBK];   // [128][32]
    __shared__ unsigned short Bs[PBN * PBK];
    const int tid  = threadIdx.x;
    const int lane = tid & 63;
    const int wid  = tid >> 6;
    const int wr   = wid >> 1, wc = wid & 1;
    const int r0   = blockIdx.y * PBM;
    const int c0   = blockIdx.x * PBN;
    const int col  = lane & 15, g = lane >> 4;

    f32x4 acc[4][4];
    #pragma unroll
    for (int m = 0; m < 4; ++m)
        #pragma unroll
        for (int n = 0; n < 4; ++n) acc[m][n] = f32x4{0.f, 0.f, 0.f, 0.f};

    const int ca = tid, cb = tid + 256;        // chunk ids (512 chunks of 8 bf16 per tile)
    const int ra1 = ca >> 2, j1 = (ca & 3) * 8;
    const int ra2 = cb >> 2, j2 = (cb & 3) * 8;

    for (int k0 = 0; k0 < EMB; k0 += PBK) {
        ushort8 va1 = *reinterpret_cast<const ushort8*>(&xb[(size_t)(r0 + ra1) * EMB + k0 + j1]);
        ushort8 va2 = *reinterpret_cast<const ushort8*>(&xb[(size_t)(r0 + ra2) * EMB + k0 + j2]);
        ushort8 vb1 = *reinterpret_cast<const ushort8*>(&wb[(size_t)(c0 + ra1) * EMB + k0 + j1]);
        ushort8 vb2 = *reinterpret_cast<const ushort8*>(&wb[(size_t)(c0 + ra2) * EMB + k0 + j2]);
        reinterpret_cast<ushort8*>(As)[ca] = va1;
        reinterpret_cast<ushort8*>(As)[cb] = va2;
        reinterpret_cast<ushort8*>(Bs)[ca] = vb1;
        reinterpret_cast<ushort8*>(Bs)[cb] = vb2;
        __syncthreads();
        bf16x8 af[4], bff[4];
        #pragma unroll
        for (int m = 0; m < 4; ++m)
            af[m] = *reinterpret_cast<const bf16x8*>(&As[(wr * 64 + m * 16 + col) * PBK + g * 8]);
        #pragma unroll
        for (int n = 0; n < 4; ++n)
            bff[n] = *reinterpret_cast<const bf16x8*>(&Bs[(wc * 64 + n * 16 + col) * PBK + g * 8]);
        #pragma unroll
        for (int m = 0; m < 4; ++m)
            #pragma unroll
            for (int n = 0; n < 4; ++n)
                acc[m][n] = __builtin_amdgcn_mfma_f32_16x16x32_bf16(af[m], bff[n], acc[m][n], 0, 0, 0);
        __syncthreads();
    }

    #pragma unroll
    for (int m = 0; m < 4; ++m) {
        #pragma unroll
        for (int n = 0; n < 4; ++n) {
            #pragma unroll
            for (int j = 0; j < 4; ++j) {
                int r = r0 + wr * 64 + m * 16 + g * 4 + j;
                int c = c0 + wc * 64 + n * 16 + col;
                float v = acc[m][n][j];
                int nb = r & 3, l = r >> 2;
                if (c < EMB) {
                    qws[((size_t)(nb * NH + (c >> 6)) * LSEQ + l) * DH + (c & 63)] = f_to_bf(v * SCALE);
                } else {
                    int c2 = c - EMB;
                    kws[((size_t)(nb * NH + (c2 >> 6)) * LSEQ + l) * DH + (c2 & 63)] = f_to_bf(v);
                }
            }
        }
    }
}

// ---- MFMA causal attention with scalar values ----
// S^T tiles: D[m][l] = sum_k K[m][k]*Q[l][k] via mfma_f32_16x16x32_bf16.
// Per wave: two l-blocks (pair, 127-pair) -> uniform 129 m-tiles per wave.
__global__ __launch_bounds__(256) void attn_mfma(const unsigned short* __restrict__ qws,
                                                 const unsigned short* __restrict__ kws,
                                                 const float* __restrict__ vw,
                                                 float* __restrict__ partials) {
    __shared__ float vs[LSEQ];      // 8 KB: vw[b][:]
    __shared__ float red[4];
    const int tid  = threadIdx.x;
    const int wid  = tid >> 6;
    const int lane = tid & 63;
    const int gid  = blockIdx.x * 4 + wid;
    const int b    = gid >> 6;       // 64 pairs per b -> b uniform per block
    const int pair = gid & 63;

    {
        const float4* src = reinterpret_cast<const float4*>(&vw[(size_t)b * LSEQ]);
        float4* dst = reinterpret_cast<float4*>(vs);
        for (int i = tid; i < LSEQ / 4; i += 256) dst[i] = src[i];
    }
    __syncthreads();

    const int col = lane & 15;
    const int g   = lane >> 4;

    float osum = 0.f;
    #pragma unroll
    for (int half = 0; half < 2; ++half) {
        const int lb = (half == 0) ? pair : 127 - pair;
        const int l0 = lb * 16;
        const unsigned short* qbase = &qws[((size_t)b * LSEQ + l0 + col) * DH + 8 * g];
        bf16x8 qf0 = *reinterpret_cast<const bf16x8*>(qbase);
        bf16x8 qf1 = *reinterpret_cast<const bf16x8*>(qbase + 32);
        float z = 0.f, o = 0.f;
        for (int t = 0; t <= lb; ++t) {
            const int m0 = t * 16;
            const unsigned short* kbase = &kws[((size_t)b * LSEQ + m0 + col) * DH + 8 * g];
            bf16x8 kf0 = *reinterpret_cast<const bf16x8*>(kbase);
            bf16x8 kf1 = *reinterpret_cast<const bf16x8*>(kbase + 32);
            f32x4 acc = {0.f, 0.f, 0.f, 0.f};
            acc = __builtin_amdgcn_mfma_f32_16x16x32_bf16(kf0, qf0, acc, 0, 0, 0);
            acc = __builtin_amdgcn_mfma_f32_16x16x32_bf16(kf1, qf1, acc, 0, 0, 0);
            float4 v4 = *reinterpret_cast<const float4*>(&vs[m0 + 4 * g]);
            float vv[4] = {v4.x, v4.y, v4.z, v4.w};
            if (t < lb) {
                #pragma unroll
                for (int j = 0; j < 4; ++j) {
                    float p = __expf(acc[j] - 16.0f);
                    z += p;
                    o += p * vv[j];
                }
            } else {
                #pragma unroll
                for (int j = 0; j < 4; ++j) {
                    if (4 * g + j <= col) {      // causal: m <= l on diagonal tile
                        float p = __expf(acc[j] - 16.0f);
                        z += p;
                        o += p * vv[j];
                    }
                }
            }
        }
        // combine the 4 row-groups -> every lane has full Z,O for its col
        z += __shfl_xor(z, 16, 64);
        z += __shfl_xor(z, 32, 64);
        o += __shfl_xor(o, 16, 64);
        o += __shfl_xor(o, 32, 64);
        osum += o / z;               // replicated 4x across g-groups
    }
    // sum over 16 cols within each group (each group holds each col exactly once;
    // the x4 replication is ACROSS groups, untouched here -> no division needed)
    osum += __shfl_xor(osum, 1, 64);
    osum += __shfl_xor(osum, 2, 64);
    osum += __shfl_xor(osum, 4, 64);
    osum += __shfl_xor(osum, 8, 64);
    if (lane == 0) red[wid] = osum;
    __syncthreads();
    if (tid == 0) partials[blockIdx.x] = red[0] + red[1] + red[2] + red[3];
}

// ---- final deterministic reduction of 1024 partials ----
__global__ void reduce_kernel(const float* __restrict__ partials, float* __restrict__ out) {
    __shared__ float red[256];
    int t = threadIdx.x;
    red[t] = partials[t] + partials[t + 256] + partials[t + 512] + partials[t + 768];
    __syncthreads();
    for (int sh = 128; sh > 0; sh >>= 1) {
        if (t < sh) red[t] += red[t + sh];
        __syncthreads();
    }
    if (t == 0) out[0] = red[0];
}

extern "C" void kernel_launch(void* const* d_in, const int* in_sizes, int n_in,
                              void* d_out, int out_size, void* d_ws, size_t ws_size,
                              hipStream_t stream) {
    const float* x    = (const float*)d_in[0];
    const float* wqkv = (const float*)d_in[1];
    const float* wout = (const float*)d_in[2];
    float* out = (float*)d_out;

    unsigned short* qws = (unsigned short*)d_ws;
    unsigned short* kws = qws + (size_t)BH * LSEQ * DH;
    unsigned short* xb  = kws + (size_t)BH * LSEQ * DH;
    unsigned short* wb  = xb + (size_t)LSEQ * NB * EMB;
    float* vw       = (float*)(wb + (size_t)2 * EMB * EMB);
    float* wsum     = vw + (size_t)BH * LSEQ;
    float* wveff    = wsum + EMB;
    float* partials = wveff + NH * EMB;

    hipLaunchKernelGGL(wsum_kernel,   dim3(EMB / 256), dim3(256), 0, stream, wout, wsum);
    hipLaunchKernelGGL(wveff_kernel,  dim3(NH * EMB / 256), dim3(256), 0, stream, wqkv, wsum, wveff);
    hipLaunchKernelGGL(vw_kernel,     dim3(LSEQ * NB / 4), dim3(256), 0, stream, x, wveff, vw);
    hipLaunchKernelGGL(tobf16_kernel, dim3(LSEQ * NB * EMB / 8 / 256), dim3(256), 0, stream,
                       x, xb, LSEQ * NB * EMB / 8);
    hipLaunchKernelGGL(tobf16_kernel, dim3(2 * EMB * EMB / 8 / 256), dim3(256), 0, stream,
                       wqkv, wb, 2 * EMB * EMB / 8);
    hipLaunchKernelGGL(proj_mfma,     dim3(2 * EMB / PBN, LSEQ * NB / PBM), dim3(256), 0, stream,
                       xb, wb, qws, kws);
    hipLaunchKernelGGL(attn_mfma,     dim3(BH * 64 / 4), dim3(256), 0, stream,
                       qws, kws, vw, partials);
    hipLaunchKernelGGL(reduce_kernel, dim3(1), dim3(256), 0, stream, partials, out);
}

// Round 4
// 211.301 us; speedup vs baseline: 6.4252x; 1.2833x over previous
//
#include <hip/hip_runtime.h>
#include <hip/hip_bf16.h>

#define LSEQ 2048
#define NB   4
#define EMB  1024
#define NH   16
#define DH   64
#define BH   (NB*NH)   // 64 head-batches
#define SCALE 0.125f   // d^-0.5

typedef unsigned short ushort8 __attribute__((ext_vector_type(8)));
typedef __attribute__((ext_vector_type(8))) short bf16x8;    // MFMA A/B frag (8 bf16)
typedef __attribute__((ext_vector_type(4))) float f32x4;     // 16x16 C/D frag
typedef __attribute__((ext_vector_type(16))) float f32x16;   // 32x32 C/D frag

__device__ __forceinline__ unsigned short f_to_bf(float f) {
    unsigned int u = __float_as_uint(f);
    return (unsigned short)((u + 0x7fffu + ((u >> 16) & 1u)) >> 16);
}

__device__ __forceinline__ void gload_lds16(const void* g, void* l) {
    __builtin_amdgcn_global_load_lds(
        (const __attribute__((address_space(1))) unsigned int*)g,
        (__attribute__((address_space(3))) unsigned int*)l, 16, 0, 0);
}

// ---- fp32 -> bf16 bulk convert (8 elems/thread) ----
__global__ __launch_bounds__(256) void tobf16_kernel(const float* __restrict__ in,
                                                     unsigned short* __restrict__ out, int n8) {
    int i = blockIdx.x * 256 + threadIdx.x;
    if (i >= n8) return;
    const float4* p = reinterpret_cast<const float4*>(in) + (size_t)i * 2;
    float4 a = p[0], b = p[1];
    ushort8 o;
    o[0] = f_to_bf(a.x); o[1] = f_to_bf(a.y); o[2] = f_to_bf(a.z); o[3] = f_to_bf(a.w);
    o[4] = f_to_bf(b.x); o[5] = f_to_bf(b.y); o[6] = f_to_bf(b.z); o[7] = f_to_bf(b.w);
    reinterpret_cast<ushort8*>(out)[i] = o;
}

// ---- wsum[e] = sum_f wout[f][e] ----
__global__ void wsum_kernel(const float* __restrict__ wout, float* __restrict__ wsum) {
    int e = blockIdx.x * 256 + threadIdx.x;
    float s = 0.f;
    #pragma unroll 8
    for (int f = 0; f < EMB; ++f) s += wout[(size_t)f * EMB + e];
    wsum[e] = s;
}

// ---- wv_eff[h][e] = sum_j wqkv[2E + h*64 + j][e] * wsum[h*64+j] ----
__global__ void wveff_kernel(const float* __restrict__ wqkv, const float* __restrict__ wsum,
                             float* __restrict__ wveff) {
    int idx = blockIdx.x * 256 + threadIdx.x;   // h*EMB + e
    int h = idx >> 10, e = idx & 1023;
    float s = 0.f;
    #pragma unroll 8
    for (int j = 0; j < DH; ++j)
        s += wqkv[(size_t)(2 * EMB + h * DH + j) * EMB + e] * wsum[h * DH + j];
    wveff[idx] = s;
}

// ---- vw[b][m] = sum_e x[m,n,e] * wv_eff[h][e],  b=n*NH+h ----
__global__ __launch_bounds__(256) void vw_kernel(const float* __restrict__ x,
                                                 const float* __restrict__ wveff,
                                                 float* __restrict__ vw) {
    int wave = threadIdx.x >> 6;
    int lane = threadIdx.x & 63;
    int r = blockIdx.x * 4 + wave;   // r = l*NB + n
    int n = r & 3, l = r >> 2;
    float acc[NH] = {};
    for (int e = lane; e < EMB; e += 64) {
        float xe = x[(size_t)r * EMB + e];
        #pragma unroll
        for (int h = 0; h < NH; ++h) acc[h] += xe * wveff[h * EMB + e];
    }
    #pragma unroll
    for (int h = 0; h < NH; ++h) {
        float v = acc[h];
        #pragma unroll
        for (int off = 32; off > 0; off >>= 1) v += __shfl_down(v, off, 64);
        if (lane == 0) vw[(size_t)(n * NH + h) * LSEQ + l] = v;
    }
}

// ---- bf16 MFMA Q/K projection (m97 structure: global_load_lds staging) ----
#define PBM 128
#define PBN 128
#define PBK 32
__global__ __launch_bounds__(256) void proj_mfma(const unsigned short* __restrict__ xb,
                                                 const unsigned short* __restrict__ wb,
                                                 unsigned short* __restrict__ qws,
                                                 unsigned short* __restrict__ kws) {
    __shared__ unsigned short As[PBM * PBK];   // [128][32] linear (gload_lds requires)
    __shared__ unsigned short Bs[PBN * PBK];
    const int tid  = threadIdx.x;
    const int lane = tid & 63;
    const int wid  = tid >> 6;
    const int wr   = wid >> 1, wc = wid & 1;
    const int r0   = blockIdx.y * PBM;
    const int c0   = blockIdx.x * PBN;
    const int col  = lane & 15, g = lane >> 4;

    f32x4 acc[4][4];
    #pragma unroll
    for (int m = 0; m < 4; ++m)
        #pragma unroll
        for (int n = 0; n < 4; ++n) acc[m][n] = f32x4{0.f, 0.f, 0.f, 0.f};

    // staging geometry: wave w stages rows [w*16, w*16+16) and [64+w*16, ...)
    // lane l -> row base + l/4, 16B slot l%4
    const int srow = lane >> 2;            // 0..15
    const int sj   = (lane & 3) * 8;       // k-offset in elems

    for (int k0 = 0; k0 < EMB; k0 += PBK) {
        gload_lds16(&xb[(size_t)(r0 + wid * 16 + srow) * EMB + k0 + sj],
                    &As[(wid * 16) * PBK]);
        gload_lds16(&xb[(size_t)(r0 + 64 + wid * 16 + srow) * EMB + k0 + sj],
                    &As[(64 + wid * 16) * PBK]);
        gload_lds16(&wb[(size_t)(c0 + wid * 16 + srow) * EMB + k0 + sj],
                    &Bs[(wid * 16) * PBK]);
        gload_lds16(&wb[(size_t)(c0 + 64 + wid * 16 + srow) * EMB + k0 + sj],
                    &Bs[(64 + wid * 16) * PBK]);
        __syncthreads();
        bf16x8 af[4], bff[4];
        #pragma unroll
        for (int m = 0; m < 4; ++m)
            af[m] = *reinterpret_cast<const bf16x8*>(&As[(wr * 64 + m * 16 + col) * PBK + g * 8]);
        #pragma unroll
        for (int n = 0; n < 4; ++n)
            bff[n] = *reinterpret_cast<const bf16x8*>(&Bs[(wc * 64 + n * 16 + col) * PBK + g * 8]);
        #pragma unroll
        for (int m = 0; m < 4; ++m)
            #pragma unroll
            for (int n = 0; n < 4; ++n)
                acc[m][n] = __builtin_amdgcn_mfma_f32_16x16x32_bf16(af[m], bff[n], acc[m][n], 0, 0, 0);
        __syncthreads();
    }

    #pragma unroll
    for (int m = 0; m < 4; ++m) {
        #pragma unroll
        for (int n = 0; n < 4; ++n) {
            #pragma unroll
            for (int j = 0; j < 4; ++j) {
                int r = r0 + wr * 64 + m * 16 + g * 4 + j;
                int c = c0 + wc * 64 + n * 16 + col;
                float v = acc[m][n][j];
                int nb = r & 3, l = r >> 2;
                if (c < EMB) {
                    qws[((size_t)(nb * NH + (c >> 6)) * LSEQ + l) * DH + (c & 63)] = f_to_bf(v * SCALE);
                } else {
                    int c2 = c - EMB;
                    kws[((size_t)(nb * NH + (c2 >> 6)) * LSEQ + l) * DH + (c2 & 63)] = f_to_bf(v);
                }
            }
        }
    }
}

// ---- MFMA causal attention, 32x32 S^T tiles with register K-prefetch ----
// D[m][l] = sum_k K[m][k]*Q[l][k] via mfma_f32_32x32x16_bf16 (4 K-steps of 16).
// Per wave: l-blocks (pair, 63-pair) -> uniform 65 m-tiles per wave.
__global__ __launch_bounds__(256) void attn_mfma(const unsigned short* __restrict__ qws,
                                                 const unsigned short* __restrict__ kws,
                                                 const float* __restrict__ vw,
                                                 float* __restrict__ partials) {
    __shared__ float vs[LSEQ];      // 8 KB: vw[b][:]
    __shared__ float red[4];
    const int tid  = threadIdx.x;
    const int wid  = tid >> 6;
    const int lane = tid & 63;
    const int gid  = blockIdx.x * 4 + wid;   // [0, 2048)
    const int b    = gid >> 5;               // 32 pairs per b -> b uniform per block
    const int pair = gid & 31;

    {
        const float4* src = reinterpret_cast<const float4*>(&vw[(size_t)b * LSEQ]);
        float4* dst = reinterpret_cast<float4*>(vs);
        for (int i = tid; i < LSEQ / 4; i += 256) dst[i] = src[i];
    }
    __syncthreads();

    const int row  = lane & 31;     // A: m-row; B: l-col; D: col
    const int half = lane >> 5;     // k-chunk select; D row offset 4*half

    float osum = 0.f;
    #pragma unroll
    for (int hh = 0; hh < 2; ++hh) {
        const int lb = hh ? 63 - pair : pair;
        const int l0 = lb * 32;
        const unsigned short* qbase = &qws[((size_t)b * LSEQ + l0 + row) * DH + 8 * half];
        bf16x8 qf[4];
        #pragma unroll
        for (int kk = 0; kk < 4; ++kk)
            qf[kk] = *reinterpret_cast<const bf16x8*>(qbase + kk * 16);

        const unsigned short* kb = &kws[((size_t)b * LSEQ + row) * DH + 8 * half];
        bf16x8 kf[4];
        #pragma unroll
        for (int kk = 0; kk < 4; ++kk)
            kf[kk] = *reinterpret_cast<const bf16x8*>(kb + kk * 16);

        float z = 0.f, o = 0.f;
        for (int t = 0; t <= lb; ++t) {
            bf16x8 kn[4];
            if (t < lb) {
                const unsigned short* knp = kb + (size_t)(t + 1) * 32 * DH;
                #pragma unroll
                for (int kk = 0; kk < 4; ++kk)
                    kn[kk] = *reinterpret_cast<const bf16x8*>(knp + kk * 16);
            }
            f32x16 acc;
            #pragma unroll
            for (int j = 0; j < 16; ++j) acc[j] = 0.f;
            #pragma unroll
            for (int kk = 0; kk < 4; ++kk)
                acc = __builtin_amdgcn_mfma_f32_32x32x16_bf16(kf[kk], qf[kk], acc, 0, 0, 0);

            const int m0 = t * 32;
            float vv[16];
            #pragma unroll
            for (int q = 0; q < 4; ++q) {
                float4 v4 = *reinterpret_cast<const float4*>(&vs[m0 + 8 * q + 4 * half]);
                vv[4 * q + 0] = v4.x; vv[4 * q + 1] = v4.y;
                vv[4 * q + 2] = v4.z; vv[4 * q + 3] = v4.w;
            }
            if (t < lb) {
                #pragma unroll
                for (int j = 0; j < 16; ++j) {
                    float p = __expf(acc[j] - 16.0f);
                    z += p;
                    o += p * vv[j];
                }
                #pragma unroll
                for (int kk = 0; kk < 4; ++kk) kf[kk] = kn[kk];
            } else {
                #pragma unroll
                for (int j = 0; j < 16; ++j) {
                    int mrow = (j & 3) + 8 * (j >> 2) + 4 * half;
                    float p = __expf(acc[j] - 16.0f);
                    p = (mrow <= row) ? p : 0.f;   // causal on diagonal tile
                    z += p;
                    o += p * vv[j];
                }
            }
        }
        z += __shfl_xor(z, 32, 64);
        o += __shfl_xor(o, 32, 64);
        osum += o / z;               // col value replicated in both halves
    }
    // sum 32 cols within each half (each half holds every col exactly once)
    osum += __shfl_xor(osum, 1, 64);
    osum += __shfl_xor(osum, 2, 64);
    osum += __shfl_xor(osum, 4, 64);
    osum += __shfl_xor(osum, 8, 64);
    osum += __shfl_xor(osum, 16, 64);
    if (lane == 0) red[wid] = osum;
    __syncthreads();
    if (tid == 0) partials[blockIdx.x] = red[0] + red[1] + red[2] + red[3];
}

// ---- final deterministic reduction of 512 partials ----
__global__ void reduce_kernel(const float* __restrict__ partials, float* __restrict__ out) {
    __shared__ float red[256];
    int t = threadIdx.x;
    red[t] = partials[t] + partials[t + 256];
    __syncthreads();
    for (int sh = 128; sh > 0; sh >>= 1) {
        if (t < sh) red[t] += red[t + sh];
        __syncthreads();
    }
    if (t == 0) out[0] = red[0];
}

extern "C" void kernel_launch(void* const* d_in, const int* in_sizes, int n_in,
                              void* d_out, int out_size, void* d_ws, size_t ws_size,
                              hipStream_t stream) {
    const float* x    = (const float*)d_in[0];
    const float* wqkv = (const float*)d_in[1];
    const float* wout = (const float*)d_in[2];
    float* out = (float*)d_out;

    unsigned short* qws = (unsigned short*)d_ws;
    unsigned short* kws = qws + (size_t)BH * LSEQ * DH;
    unsigned short* xb  = kws + (size_t)BH * LSEQ * DH;
    unsigned short* wb  = xb + (size_t)LSEQ * NB * EMB;
    float* vw       = (float*)(wb + (size_t)2 * EMB * EMB);
    float* wsum     = vw + (size_t)BH * LSEQ;
    float* wveff    = wsum + EMB;
    float* partials = wveff + NH * EMB;

    hipLaunchKernelGGL(tobf16_kernel, dim3(LSEQ * NB * EMB / 8 / 256), dim3(256), 0, stream,
                       x, xb, LSEQ * NB * EMB / 8);
    hipLaunchKernelGGL(tobf16_kernel, dim3(2 * EMB * EMB / 8 / 256), dim3(256), 0, stream,
                       wqkv, wb, 2 * EMB * EMB / 8);
    hipLaunchKernelGGL(wsum_kernel,   dim3(EMB / 256), dim3(256), 0, stream, wout, wsum);
    hipLaunchKernelGGL(wveff_kernel,  dim3(NH * EMB / 256), dim3(256), 0, stream, wqkv, wsum, wveff);
    hipLaunchKernelGGL(vw_kernel,     dim3(LSEQ * NB / 4), dim3(256), 0, stream, x, wveff, vw);
    hipLaunchKernelGGL(proj_mfma,     dim3(2 * EMB / PBN, LSEQ * NB / PBM), dim3(256), 0, stream,
                       xb, wb, qws, kws);
    hipLaunchKernelGGL(attn_mfma,     dim3(BH * 32 / 4), dim3(256), 0, stream,
                       qws, kws, vw, partials);
    hipLaunchKernelGGL(reduce_kernel, dim3(1), dim3(256), 0, stream, partials, out);
}

// Round 5
// 166.052 us; speedup vs baseline: 8.1760x; 1.2725x over previous
//
#include <hip/hip_runtime.h>
#include <hip/hip_bf16.h>

#define LSEQ 2048
#define NB   4
#define EMB  1024
#define NH   16
#define DH   64
#define BH   (NB*NH)   // 64 head-batches
#define SCALE 0.125f   // d^-0.5

typedef unsigned short ushort8 __attribute__((ext_vector_type(8)));
typedef __attribute__((ext_vector_type(8))) short bf16x8;    // MFMA A/B frag (8 bf16)
typedef __attribute__((ext_vector_type(4))) float f32x4;     // 16x16 C/D frag
typedef __attribute__((ext_vector_type(16))) float f32x16;   // 32x32 C/D frag

__device__ __forceinline__ unsigned short f_to_bf(float f) {
    unsigned int u = __float_as_uint(f);
    return (unsigned short)((u + 0x7fffu + ((u >> 16) & 1u)) >> 16);
}

__device__ __forceinline__ void gload_lds16(const void* g, void* l) {
    __builtin_amdgcn_global_load_lds(
        (const __attribute__((address_space(1))) unsigned int*)g,
        (__attribute__((address_space(3))) unsigned int*)l, 16, 0, 0);
}

// ---- fp32 -> bf16 bulk convert (8 elems/thread) ----
__global__ __launch_bounds__(256) void tobf16_kernel(const float* __restrict__ in,
                                                     unsigned short* __restrict__ out, int n8) {
    int i = blockIdx.x * 256 + threadIdx.x;
    if (i >= n8) return;
    const float4* p = reinterpret_cast<const float4*>(in) + (size_t)i * 2;
    float4 a = p[0], b = p[1];
    ushort8 o;
    o[0] = f_to_bf(a.x); o[1] = f_to_bf(a.y); o[2] = f_to_bf(a.z); o[3] = f_to_bf(a.w);
    o[4] = f_to_bf(b.x); o[5] = f_to_bf(b.y); o[6] = f_to_bf(b.z); o[7] = f_to_bf(b.w);
    reinterpret_cast<ushort8*>(out)[i] = o;
}

// ---- wsum[e] = sum_f wout[f][e], 2-stage for parallelism ----
__global__ __launch_bounds__(256) void wsum_part_kernel(const float* __restrict__ wout,
                                                        float* __restrict__ wpart) {
    int fc = blockIdx.x >> 2;          // 32 chunks of 32 rows
    int e  = (blockIdx.x & 3) * 256 + threadIdx.x;
    float s = 0.f;
    #pragma unroll 8
    for (int f = fc * 32; f < fc * 32 + 32; ++f) s += wout[(size_t)f * EMB + e];
    wpart[(size_t)fc * EMB + e] = s;
}
__global__ __launch_bounds__(256) void wsum_final_kernel(const float* __restrict__ wpart,
                                                         float* __restrict__ wsum) {
    int e = blockIdx.x * 256 + threadIdx.x;
    float s = 0.f;
    #pragma unroll
    for (int c = 0; c < 32; ++c) s += wpart[(size_t)c * EMB + e];
    wsum[e] = s;
}

// ---- wv_eff[h][e] = sum_j wqkv[2E + h*64 + j][e] * wsum[h*64+j] ----
__global__ void wveff_kernel(const float* __restrict__ wqkv, const float* __restrict__ wsum,
                             float* __restrict__ wveff) {
    int idx = blockIdx.x * 256 + threadIdx.x;   // h*EMB + e
    int h = idx >> 10, e = idx & 1023;
    float s = 0.f;
    #pragma unroll 8
    for (int j = 0; j < DH; ++j)
        s += wqkv[(size_t)(2 * EMB + h * DH + j) * EMB + e] * wsum[h * DH + j];
    wveff[idx] = s;
}

// ---- vw[b][m] = sum_e x[m,n,e] * wv_eff[h][e],  b=n*NH+h ----
__global__ __launch_bounds__(256) void vw_kernel(const float* __restrict__ x,
                                                 const float* __restrict__ wveff,
                                                 float* __restrict__ vw) {
    int wave = threadIdx.x >> 6;
    int lane = threadIdx.x & 63;
    int r = blockIdx.x * 4 + wave;   // r = l*NB + n
    int n = r & 3, l = r >> 2;
    float acc[NH] = {};
    for (int e = lane; e < EMB; e += 64) {
        float xe = x[(size_t)r * EMB + e];
        #pragma unroll
        for (int h = 0; h < NH; ++h) acc[h] += xe * wveff[h * EMB + e];
    }
    #pragma unroll
    for (int h = 0; h < NH; ++h) {
        float v = acc[h];
        #pragma unroll
        for (int off = 32; off > 0; off >>= 1) v += __shfl_down(v, off, 64);
        if (lane == 0) vw[(size_t)(n * NH + h) * LSEQ + l] = v;
    }
}

// ---- bf16 MFMA Q/K projection (m97 structure: global_load_lds staging) ----
#define PBM 128
#define PBN 128
#define PBK 32
__global__ __launch_bounds__(256) void proj_mfma(const unsigned short* __restrict__ xb,
                                                 const unsigned short* __restrict__ wb,
                                                 unsigned short* __restrict__ qws,
                                                 unsigned short* __restrict__ kws) {
    __shared__ unsigned short As[PBM * PBK];   // [128][32] linear (gload_lds requires)
    __shared__ unsigned short Bs[PBN * PBK];
    const int tid  = threadIdx.x;
    const int lane = tid & 63;
    const int wid  = tid >> 6;
    const int wr   = wid >> 1, wc = wid & 1;
    const int r0   = blockIdx.y * PBM;
    const int c0   = blockIdx.x * PBN;
    const int col  = lane & 15, g = lane >> 4;

    f32x4 acc[4][4];
    #pragma unroll
    for (int m = 0; m < 4; ++m)
        #pragma unroll
        for (int n = 0; n < 4; ++n) acc[m][n] = f32x4{0.f, 0.f, 0.f, 0.f};

    const int srow = lane >> 2;            // 0..15
    const int sj   = (lane & 3) * 8;       // k-offset in elems

    for (int k0 = 0; k0 < EMB; k0 += PBK) {
        gload_lds16(&xb[(size_t)(r0 + wid * 16 + srow) * EMB + k0 + sj],
                    &As[(wid * 16) * PBK]);
        gload_lds16(&xb[(size_t)(r0 + 64 + wid * 16 + srow) * EMB + k0 + sj],
                    &As[(64 + wid * 16) * PBK]);
        gload_lds16(&wb[(size_t)(c0 + wid * 16 + srow) * EMB + k0 + sj],
                    &Bs[(wid * 16) * PBK]);
        gload_lds16(&wb[(size_t)(c0 + 64 + wid * 16 + srow) * EMB + k0 + sj],
                    &Bs[(64 + wid * 16) * PBK]);
        __syncthreads();
        bf16x8 af[4], bff[4];
        #pragma unroll
        for (int m = 0; m < 4; ++m)
            af[m] = *reinterpret_cast<const bf16x8*>(&As[(wr * 64 + m * 16 + col) * PBK + g * 8]);
        #pragma unroll
        for (int n = 0; n < 4; ++n)
            bff[n] = *reinterpret_cast<const bf16x8*>(&Bs[(wc * 64 + n * 16 + col) * PBK + g * 8]);
        #pragma unroll
        for (int m = 0; m < 4; ++m)
            #pragma unroll
            for (int n = 0; n < 4; ++n)
                acc[m][n] = __builtin_amdgcn_mfma_f32_16x16x32_bf16(af[m], bff[n], acc[m][n], 0, 0, 0);
        __syncthreads();
    }

    #pragma unroll
    for (int m = 0; m < 4; ++m) {
        #pragma unroll
        for (int n = 0; n < 4; ++n) {
            #pragma unroll
            for (int j = 0; j < 4; ++j) {
                int r = r0 + wr * 64 + m * 16 + g * 4 + j;
                int c = c0 + wc * 64 + n * 16 + col;
                float v = acc[m][n][j];
                int nb = r & 3, l = r >> 2;
                if (c < EMB) {
                    qws[((size_t)(nb * NH + (c >> 6)) * LSEQ + l) * DH + (c & 63)] = f_to_bf(v * SCALE);
                } else {
                    int c2 = c - EMB;
                    kws[((size_t)(nb * NH + (c2 >> 6)) * LSEQ + l) * DH + (c2 & 63)] = f_to_bf(v);
                }
            }
        }
    }
}

// ---- attn helpers ----
__device__ __forceinline__ void load_kfrag(const unsigned short* kb, int tile, bf16x8* kf) {
    const unsigned short* p = kb + (size_t)tile * 32 * DH;
    #pragma unroll
    for (int kk = 0; kk < 4; ++kk)
        kf[kk] = *reinterpret_cast<const bf16x8*>(p + kk * 16);
}
__device__ __forceinline__ f32x16 mfma_tile(const bf16x8* kf, const bf16x8* qf) {
    f32x16 acc;
    #pragma unroll
    for (int j = 0; j < 16; ++j) acc[j] = 0.f;
    #pragma unroll
    for (int kk = 0; kk < 4; ++kk)
        acc = __builtin_amdgcn_mfma_f32_32x32x16_bf16(kf[kk], qf[kk], acc, 0, 0, 0);
    return acc;
}
__device__ __forceinline__ void expacc(const f32x16& acc, const float* vs, int m0, int half,
                                       float& z, float& o) {
    #pragma unroll
    for (int q = 0; q < 4; ++q) {
        float4 v4 = *reinterpret_cast<const float4*>(&vs[m0 + 8 * q + 4 * half]);
        float vvq[4] = {v4.x, v4.y, v4.z, v4.w};
        #pragma unroll
        for (int j = 0; j < 4; ++j) {
            float p = __expf(acc[4 * q + j] - 16.0f);
            z += p;
            o += p * vvq[j];
        }
    }
}
__device__ __forceinline__ void expacc_diag(const f32x16& acc, const float* vs, int m0, int half,
                                            int row, float& z, float& o) {
    #pragma unroll
    for (int q = 0; q < 4; ++q) {
        float4 v4 = *reinterpret_cast<const float4*>(&vs[m0 + 8 * q + 4 * half]);
        float vvq[4] = {v4.x, v4.y, v4.z, v4.w};
        #pragma unroll
        for (int j = 0; j < 4; ++j) {
            int mrow = j + 8 * q + 4 * half;
            float p = __expf(acc[4 * q + j] - 16.0f);
            p = (mrow <= row) ? p : 0.f;   // causal on diagonal tile
            z += p;
            o += p * vvq[j];
        }
    }
}

// ---- MFMA causal attention, 32x32 S^T tiles, ILP-2 over m-tiles ----
__global__ __launch_bounds__(256) void attn_mfma(const unsigned short* __restrict__ qws,
                                                 const unsigned short* __restrict__ kws,
                                                 const float* __restrict__ vw,
                                                 float* __restrict__ partials) {
    __shared__ float vs[LSEQ];      // 8 KB: vw[b][:]
    __shared__ float red[4];
    const int tid  = threadIdx.x;
    const int wid  = tid >> 6;
    const int lane = tid & 63;
    const int gid  = blockIdx.x * 4 + wid;   // [0, 2048)
    const int b    = gid >> 5;               // uniform per block
    const int pair = gid & 31;

    {
        const float4* src = reinterpret_cast<const float4*>(&vw[(size_t)b * LSEQ]);
        float4* dst = reinterpret_cast<float4*>(vs);
        for (int i = tid; i < LSEQ / 4; i += 256) dst[i] = src[i];
    }
    __syncthreads();

    const int row  = lane & 31;     // A: m-row; B: l-col; D: col
    const int half = lane >> 5;     // k-chunk select; D row offset 4*half

    float osum = 0.f;
    #pragma unroll
    for (int hh = 0; hh < 2; ++hh) {
        const int lb = hh ? 63 - pair : pair;
        const int l0 = lb * 32;
        const unsigned short* qbase = &qws[((size_t)b * LSEQ + l0 + row) * DH + 8 * half];
        bf16x8 qf[4];
        #pragma unroll
        for (int kk = 0; kk < 4; ++kk)
            qf[kk] = *reinterpret_cast<const bf16x8*>(qbase + kk * 16);

        const unsigned short* kb = &kws[((size_t)b * LSEQ + row) * DH + 8 * half];

        float z = 0.f, o = 0.f;
        int t = 0;
        // ILP-2 main loop over non-diagonal tiles
        for (; t + 1 < lb; t += 2) {
            bf16x8 ka[4], kc[4];
            load_kfrag(kb, t, ka);
            load_kfrag(kb, t + 1, kc);
            __builtin_amdgcn_s_setprio(1);
            f32x16 accA = mfma_tile(ka, qf);
            f32x16 accB = mfma_tile(kc, qf);
            __builtin_amdgcn_s_setprio(0);
            expacc(accA, vs, t * 32, half, z, o);
            expacc(accB, vs, (t + 1) * 32, half, z, o);
        }
        if (t < lb) {               // leftover single non-diagonal tile
            bf16x8 ka[4];
            load_kfrag(kb, t, ka);
            f32x16 accA = mfma_tile(ka, qf);
            expacc(accA, vs, t * 32, half, z, o);
            ++t;
        }
        {                           // diagonal tile t == lb
            bf16x8 ka[4];
            load_kfrag(kb, lb, ka);
            f32x16 accA = mfma_tile(ka, qf);
            expacc_diag(accA, vs, lb * 32, half, row, z, o);
        }
        z += __shfl_xor(z, 32, 64);
        o += __shfl_xor(o, 32, 64);
        osum += o / z;               // col value replicated in both halves
    }
    // sum 32 cols within each half (each half holds every col exactly once)
    osum += __shfl_xor(osum, 1, 64);
    osum += __shfl_xor(osum, 2, 64);
    osum += __shfl_xor(osum, 4, 64);
    osum += __shfl_xor(osum, 8, 64);
    osum += __shfl_xor(osum, 16, 64);
    if (lane == 0) red[wid] = osum;
    __syncthreads();
    if (tid == 0) partials[blockIdx.x] = red[0] + red[1] + red[2] + red[3];
}

// ---- final deterministic reduction of 512 partials ----
__global__ void reduce_kernel(const float* __restrict__ partials, float* __restrict__ out) {
    __shared__ float red[256];
    int t = threadIdx.x;
    red[t] = partials[t] + partials[t + 256];
    __syncthreads();
    for (int sh = 128; sh > 0; sh >>= 1) {
        if (t < sh) red[t] += red[t + sh];
        __syncthreads();
    }
    if (t == 0) out[0] = red[0];
}

extern "C" void kernel_launch(void* const* d_in, const int* in_sizes, int n_in,
                              void* d_out, int out_size, void* d_ws, size_t ws_size,
                              hipStream_t stream) {
    const float* x    = (const float*)d_in[0];
    const float* wqkv = (const float*)d_in[1];
    const float* wout = (const float*)d_in[2];
    float* out = (float*)d_out;

    unsigned short* qws = (unsigned short*)d_ws;
    unsigned short* kws = qws + (size_t)BH * LSEQ * DH;
    unsigned short* xb  = kws + (size_t)BH * LSEQ * DH;
    unsigned short* wb  = xb + (size_t)LSEQ * NB * EMB;
    float* vw       = (float*)(wb + (size_t)2 * EMB * EMB);
    float* wsum     = vw + (size_t)BH * LSEQ;
    float* wveff    = wsum + EMB;
    float* partials = wveff + NH * EMB;
    float* wpart    = partials + 1024;

    hipLaunchKernelGGL(tobf16_kernel, dim3(LSEQ * NB * EMB / 8 / 256), dim3(256), 0, stream,
                       x, xb, LSEQ * NB * EMB / 8);
    hipLaunchKernelGGL(tobf16_kernel, dim3(2 * EMB * EMB / 8 / 256), dim3(256), 0, stream,
                       wqkv, wb, 2 * EMB * EMB / 8);
    hipLaunchKernelGGL(wsum_part_kernel,  dim3(128), dim3(256), 0, stream, wout, wpart);
    hipLaunchKernelGGL(wsum_final_kernel, dim3(EMB / 256), dim3(256), 0, stream, wpart, wsum);
    hipLaunchKernelGGL(wveff_kernel,  dim3(NH * EMB / 256), dim3(256), 0, stream, wqkv, wsum, wveff);
    hipLaunchKernelGGL(vw_kernel,     dim3(LSEQ * NB / 4), dim3(256), 0, stream, x, wveff, vw);
    hipLaunchKernelGGL(proj_mfma,     dim3(2 * EMB / PBN, LSEQ * NB / PBM), dim3(256), 0, stream,
                       xb, wb, qws, kws);
    hipLaunchKernelGGL(attn_mfma,     dim3(BH * 32 / 4), dim3(256), 0, stream,
                       qws, kws, vw, partials);
    hipLaunchKernelGGL(reduce_kernel, dim3(1), dim3(256), 0, stream, partials, out);
}